// Round 19
// baseline (161.066 us; speedup 1.0000x reference)
//
#include <hip/hip_runtime.h>

#define S_LEN 2048
#define BATCH 2
#define NH 32
#define NKV 8
#define HD 64
#define HID 2048
#define NTOK (BATCH * S_LEN)   // 4096
#define NQKV 3072              // 2048 Q + 512 K + 512 V
#define SC_Q 0.18033688011112042f   // 0.125 * log2(e)

typedef __attribute__((ext_vector_type(8))) __bf16 bf16x8;
typedef __attribute__((ext_vector_type(4))) float f32x4;
typedef __attribute__((ext_vector_type(4))) float f32x4v;
typedef __attribute__((ext_vector_type(4))) ushort u16x4;

__device__ inline ushort f2b(float f) {
    union { float f; unsigned u; } x{f};
    unsigned r = (x.u + 0x7fff + ((x.u >> 16) & 1)) >> 16;
    return (ushort)r;
}
__device__ inline float b2f(ushort u) {
    union { unsigned u; float f; } x{(unsigned)u << 16};
    return x.f;
}
__device__ inline float ex2(float x) { return __builtin_amdgcn_exp2f(x); }

// ---------------- fused fp32 -> bf16 conversion (grid-stride, nt loads) ----------------
__global__ __launch_bounds__(256) void cvt_all(const float* __restrict__ hidden,
                                               const float* __restrict__ Wq,
                                               const float* __restrict__ Wk,
                                               const float* __restrict__ Wv,
                                               const float* __restrict__ Wo,
                                               ushort* __restrict__ hb,
                                               ushort* __restrict__ wqkv,
                                               ushort* __restrict__ wo) {
    for (int bid = blockIdx.x; bid < 18432; bid += gridDim.x) {
        const float* src;
        ushort* dst;
        int off;
        if (bid < 8192)        { src = hidden; dst = hb;                              off = bid; }
        else if (bid < 12288)  { src = Wq;     dst = wqkv;                            off = bid - 8192; }
        else if (bid < 13312)  { src = Wk;     dst = wqkv + (size_t)2048 * 2048;      off = bid - 12288; }
        else if (bid < 14336)  { src = Wv;     dst = wqkv + (size_t)2560 * 2048;      off = bid - 13312; }
        else                   { src = Wo;     dst = wo;                              off = bid - 14336; }
        size_t i = (size_t)off * 256 + threadIdx.x;
        f32x4v v = __builtin_nontemporal_load((const f32x4v*)src + i);
        u16x4 o = {f2b(v[0]), f2b(v[1]), f2b(v[2]), f2b(v[3])};
        *((u16x4*)dst + i) = o;
    }
}

// ---------------- global -> LDS async helper ----------------
__device__ inline void gl_lds16(const void* g, void* l) {
    __builtin_amdgcn_global_load_lds((const __attribute__((address_space(1))) void*)g,
                                     (__attribute__((address_space(3))) void*)l, 16, 0, 0);
}

// ---------------- QKV GEMM: 256x192, 8 waves, SINGLE barrier per K-tile ----------------
__global__ __launch_bounds__(512, 2) void gemmQKV(const ushort* __restrict__ A,
                                                  const ushort* __restrict__ B,
                                                  ushort* __restrict__ Qd,
                                                  ushort* __restrict__ Kd,
                                                  ushort* __restrict__ Vd,
                                                  int M, int N, int K) {
    constexpr int CF = 3;
    constexpr int ABYTES = 256 * 64 * 2;   // 32 KB
    constexpr int BBYTES = 192 * 64 * 2;   // 24 KB
    __shared__ __align__(16) char lds[2][ABYTES + BBYTES];   // 112 KB
    const int tid = threadIdx.x, lane = tid & 63, w = tid >> 6;
    const int wm = w >> 2, wn = w & 3, l15 = lane & 15, lg = lane >> 4;

    const int nbx = gridDim.x;
    int lid = blockIdx.y * nbx + blockIdx.x;
    const int cpx = (nbx * gridDim.y) >> 3;
    int swzb = (lid & 7) * cpx + (lid >> 3);
    const int m0 = (swzb / nbx) * 256, n0 = (swzb % nbx) * (CF * 64);

    const int srow = tid >> 3;
    const int scol = ((tid & 7) ^ (srow & 7)) * 8;
    const ushort* Ag = A + (size_t)(m0 + srow) * K + scol;
    const ushort* Bg = B + (size_t)(n0 + srow) * K + scol;

    auto stage = [&](int buf, int k0) {
        char* base = &lds[buf][0];
#pragma unroll
        for (int j = 0; j < CF; j++)
            gl_lds16(Bg + (size_t)(j * 64) * K + k0, base + ABYTES + (j * 64 + w * 8) * 128);
#pragma unroll
        for (int j = 0; j < 4; j++)
            gl_lds16(Ag + (size_t)(j * 64) * K + k0, base + (j * 64 + w * 8) * 128);
    };

    f32x4 acc[8][CF] = {};

    stage(0, 0);

    const int NT = K >> 6;
    const int sw = (l15 & 7) * 16;
    const int po0 = (lg * 16) ^ sw, po1 = (64 + lg * 16) ^ sw;

    for (int t = 0; t < NT; ++t) {
        asm volatile("s_waitcnt vmcnt(0)" ::: "memory");
        __builtin_amdgcn_s_barrier();
        __builtin_amdgcn_sched_barrier(0);
        if (t + 1 < NT) stage((t + 1) & 1, (t + 1) << 6);
        __builtin_amdgcn_sched_barrier(0);

        const char* pa = &lds[t & 1][0] + (wm * 128 + l15) * 128;
        const char* pb = &lds[t & 1][ABYTES] + (wn * CF * 16 + l15) * 128;

        bf16x8 bf_[2][CF];
#pragma unroll
        for (int j = 0; j < CF; j++) {
            bf_[0][j] = *(const bf16x8*)(pb + j * 2048 + po0);
            bf_[1][j] = *(const bf16x8*)(pb + j * 2048 + po1);
        }
        bf16x8 a_[2][8];
#pragma unroll
        for (int i = 0; i < 8; i++) {
            a_[0][i] = *(const bf16x8*)(pa + i * 2048 + po0);
            a_[1][i] = *(const bf16x8*)(pa + i * 2048 + po1);
        }
        __builtin_amdgcn_s_setprio(1);
#pragma unroll
        for (int ks = 0; ks < 2; ks++)
#pragma unroll
            for (int i = 0; i < 8; i++)
#pragma unroll
                for (int j = 0; j < CF; j++)
                    acc[i][j] = __builtin_amdgcn_mfma_f32_16x16x32_bf16(a_[ks][i], bf_[ks][j], acc[i][j], 0, 0, 0);
        __builtin_amdgcn_s_setprio(0);
    }

    const int mr = m0 + wm * 128 + lg * 4;
#pragma unroll
    for (int j = 0; j < CF; j++) {
        int cb = n0 + wn * CF * 16 + j * 16;
        ushort* dst;
        int dstride, colb;
        if (cb < 2048)      { dst = Qd; dstride = 2048; colb = cb + l15; }
        else if (cb < 2560) { dst = Kd; dstride = 512;  colb = cb - 2048 + l15; }
        else                { dst = Vd; dstride = 512;  colb = cb - 2560 + l15; }
#pragma unroll
        for (int i = 0; i < 8; i++)
#pragma unroll
            for (int r = 0; r < 4; r++)
                dst[(size_t)(mr + i * 16 + r) * dstride + colb] = f2b(acc[i][j][r]);
    }
}

// ---------------- O GEMM: 128x256, 8 waves, 3-buffer 2-deep, SINGLE barrier ----------------
__global__ __launch_bounds__(512, 2) void gemmO(const ushort* __restrict__ A,
                                                const ushort* __restrict__ B,
                                                float* __restrict__ C,
                                                int M, int N, int K) {
    constexpr int ABYTES = 128 * 64 * 2;   // 16 KB
    constexpr int BBYTES = 256 * 64 * 2;   // 32 KB
    __shared__ __align__(16) char lds[3][ABYTES + BBYTES];   // 144 KB
    const int tid = threadIdx.x, lane = tid & 63, w = tid >> 6;
    const int wm = w >> 2, wn = w & 3, l15 = lane & 15, lg = lane >> 4;

    const int nbx = gridDim.x;   // 8
    int lid = blockIdx.y * nbx + blockIdx.x;
    const int cpx = (nbx * gridDim.y) >> 3;   // 32
    int swzb = (lid & 7) * cpx + (lid >> 3);
    const int m0 = (swzb / nbx) * 128, n0 = (swzb % nbx) * 256;

    const int srow = tid >> 3;
    const int scol = ((tid & 7) ^ (srow & 7)) * 8;
    const ushort* Ag = A + (size_t)(m0 + srow) * K + scol;
    const ushort* Bg = B + (size_t)(n0 + srow) * K + scol;

    auto stage = [&](int buf, int k0) {
        char* base = &lds[buf][0];
        gl_lds16(Ag + k0,                   base + (w * 8) * 128);
        gl_lds16(Ag + (size_t)64 * K + k0,  base + (64 + w * 8) * 128);
#pragma unroll
        for (int j = 0; j < 4; j++)
            gl_lds16(Bg + (size_t)(j * 64) * K + k0, base + ABYTES + (j * 64 + w * 8) * 128);
    };

    f32x4 acc[4][4] = {};

    stage(0, 0);
    stage(1, 64);

    const int NT = K >> 6;
    const int sw = (l15 & 7) * 16;
    const int po0 = (lg * 16) ^ sw, po1 = (64 + lg * 16) ^ sw;

    int i0 = 0, i1 = 1, i2 = 2;
    for (int t = 0; t < NT; ++t) {
        if (t < NT - 1) asm volatile("s_waitcnt vmcnt(6)" ::: "memory");
        else            asm volatile("s_waitcnt vmcnt(0)" ::: "memory");
        __builtin_amdgcn_s_barrier();
        __builtin_amdgcn_sched_barrier(0);
        if (t + 2 < NT) stage(i2, (t + 2) << 6);
        __builtin_amdgcn_sched_barrier(0);

        const char* pa = &lds[i0][0] + (wm * 64 + l15) * 128;
        const char* pb = &lds[i0][ABYTES] + (wn * 64 + l15) * 128;

        bf16x8 a_[2][4], b_[2][4];
#pragma unroll
        for (int i = 0; i < 4; i++) {
            a_[0][i] = *(const bf16x8*)(pa + i * 2048 + po0);
            a_[1][i] = *(const bf16x8*)(pa + i * 2048 + po1);
            b_[0][i] = *(const bf16x8*)(pb + i * 2048 + po0);
            b_[1][i] = *(const bf16x8*)(pb + i * 2048 + po1);
        }
        __builtin_amdgcn_s_setprio(1);
#pragma unroll
        for (int ks = 0; ks < 2; ks++)
#pragma unroll
            for (int i = 0; i < 4; i++)
#pragma unroll
                for (int j = 0; j < 4; j++)
                    acc[i][j] = __builtin_amdgcn_mfma_f32_16x16x32_bf16(a_[ks][i], b_[ks][j], acc[i][j], 0, 0, 0);
        __builtin_amdgcn_s_setprio(0);

        int tt = i0; i0 = i1; i1 = i2; i2 = tt;
    }

    const int mr = m0 + wm * 64 + lg * 4, nc = n0 + wn * 64 + l15;
#pragma unroll
    for (int i = 0; i < 4; i++)
#pragma unroll
        for (int j = 0; j < 4; j++)
#pragma unroll
            for (int r = 0; r < 4; r++)
                C[(size_t)(mr + i * 16 + r) * N + nc + j * 16] = acc[i][j][r];
}

// ---------------- RoPE for K only (in place): Kb [NTOK][512] ----------------
__global__ __launch_bounds__(256) void rope_k(ushort* __restrict__ Kb) {
    int idx = blockIdx.x * 256 + threadIdx.x;   // NTOK * 8 * 4
    int t = idx >> 5, rem = idx & 31;
    int hh = rem >> 2, q8 = rem & 3;
    float pos = (float)(t & (S_LEN - 1));
    ushort* base = Kb + (size_t)t * 512 + hh * 64 + q8 * 8;
    ushort4 v0 = *(ushort4*)base, v1 = *(ushort4*)(base + 4);
    ushort4 u0 = *(ushort4*)(base + 32), u1 = *(ushort4*)(base + 36);
    ushort lo[8] = {v0.x, v0.y, v0.z, v0.w, v1.x, v1.y, v1.z, v1.w};
    ushort hi[8] = {u0.x, u0.y, u0.z, u0.w, u1.x, u1.y, u1.z, u1.w};
#pragma unroll
    for (int e = 0; e < 8; e++) {
        float f = ex2(-(float)(q8 * 8 + e) * 0.4152410118609203f);
        float sv, cv;
        __sincosf(pos * f, &sv, &cv);
        float x1 = b2f(lo[e]), x2 = b2f(hi[e]);
        lo[e] = f2b(x1 * cv - x2 * sv);
        hi[e] = f2b(x2 * cv + x1 * sv);
    }
    *(ushort4*)base        = make_ushort4(lo[0], lo[1], lo[2], lo[3]);
    *(ushort4*)(base + 4)  = make_ushort4(lo[4], lo[5], lo[6], lo[7]);
    *(ushort4*)(base + 32) = make_ushort4(hi[0], hi[1], hi[2], hi[3]);
    *(ushort4*)(base + 36) = make_ushort4(hi[4], hi[5], hi[6], hi[7]);
}

// ---------------- V transpose: Vb [NTOK][512] -> Vt [b][kvh][64][S] ----------------
__global__ __launch_bounds__(256) void transpose_v(const ushort* __restrict__ V,
                                                   ushort* __restrict__ Vt) {
    __shared__ ushort tile[32][33];
    int bz = blockIdx.z, b = bz >> 3, kvh = bz & 7;
    int s0 = blockIdx.x * 32, d0 = blockIdx.y * 32;
    int tx = threadIdx.x & 31, ty = threadIdx.x >> 5;
#pragma unroll
    for (int i = 0; i < 4; i++)
        tile[ty + i * 8][tx] = V[(size_t)(b * S_LEN + s0 + ty + i * 8) * 512 + kvh * 64 + d0 + tx];
    __syncthreads();
#pragma unroll
    for (int i = 0; i < 4; i++)
        Vt[((size_t)((b * 8 + kvh) * 64 + d0 + ty + i * 8)) * S_LEN + s0 + tx] = tile[tx][ty + i * 8];
}

// ---------------- Flash attention (causal, GQA) ----------------
// KVBLK=128 staged as two 64-kv sub-buffers (verified swizzle reused).
// ONE vmcnt(0)+barrier per 128-tile (loads issued a full tile earlier);
// two compute subphases h64=0,1 with no sync between. Last tile: subtile A's
// h64=1 slice fully masked -> skipped. 2 q-subtiles/wave; no online max;
// row sums via MFMA-ones. Q roped+scaled in-register.
__global__ __launch_bounds__(256) void attn_k(const ushort* __restrict__ Q,   // stride 2048
                                              const ushort* __restrict__ Kc,  // stride 512 (roped)
                                              const ushort* __restrict__ Vt,
                                              ushort* __restrict__ O) {
    __shared__ __align__(16) ushort K_lds[2][2][4096];   // 32 KB
    __shared__ __align__(16) ushort V_lds[2][2][4096];   // 32 KB
    const int lane = threadIdx.x & 63, w = threadIdx.x >> 6;
    const int l15 = lane & 15, lg = lane >> 4;

    int lid = blockIdx.y * 8 + blockIdx.x;
    int swz = (lid & 7) * 64 + (lid >> 3);
    const int ps = swz & 7;
    const int bh = swz >> 3;
    const int b = bh >> 5, h = bh & 31, kvh = h >> 2;

    const ushort* kSrc[2];
    const ushort* vSrc[2];
    int dstU[2];
#pragma unroll
    for (int j = 0; j < 2; j++) {
        int u = w * 2 + j;
        int row = u * 8 + (lane >> 3);
        int po = (lane & 7) * 16;
        int fr = ((row & 3) | (((row >> 3) & 1) << 2)) << 4;
        int dus = (po ^ fr) >> 1;
        kSrc[j] = Kc + (size_t)(b * S_LEN + row) * 512 + kvh * 64 + dus;
        vSrc[j] = Vt + ((size_t)((b * 8 + kvh) * 64 + row)) * S_LEN + dus;
        dstU[j] = u * 512;
    }

    int fr_k = ((l15 & 3) | (((l15 >> 2) & 1) << 2)) << 4;
    int kbase = 1024 * (l15 >> 2) + 128 * (l15 & 3) + ((lg * 16) ^ (fr_k & 48));
    int k6 = (fr_k >> 6) & 1;
    int kb0 = kbase + 64 * k6, kb1 = kbase + 64 * (1 - k6);
    int fr_v = ((l15 & 3) | (((l15 >> 3) & 1) << 2)) << 4;
    int vbase = 128 * l15 + ((lg * 16) ^ (fr_v & 48));
    int v6 = (fr_v >> 6) & 1;
    int vb0 = vbase + 64 * v6, vb1 = vbase + 64 * (1 - v6);

    bf16x8 onesf;
#pragma unroll
    for (int i = 0; i < 8; i++) onesf[i] = (__bf16)1.0f;

    auto ropeq = [&](bf16x8& q0, bf16x8& q1, int qrow) {
        float pos = (float)qrow;
#pragma unroll
        for (int e = 0; e < 8; e++) {
            float f = ex2(-(float)(lg * 8 + e) * 0.4152410118609203f);
            float sv, cv;
            __sincosf(pos * f, &sv, &cv);
            float x1 = (float)q0[e], x2 = (float)q1[e];
            q0[e] = (__bf16)((x1 * cv - x2 * sv) * SC_Q);
            q1[e] = (__bf16)((x2 * cv + x1 * sv) * SC_Q);
        }
    };

    // local mask bound (same for A@h0 and B@h1): kvp <= w*16 + l15
    const int mloc = w * 16 + l15;

    for (int half = 0; half < 2; ++half) {
        const int pp = half ? (15 - ps) : ps;
        const int q0A = pp * 128 + w * 16, q0B = q0A + 64;
        const int qrowA = q0A + l15, qrowB = q0B + l15;
        const int TL = pp + 1;   // 128-kv tiles

        const ushort* qpA = Q + (size_t)(b * S_LEN + qrowA) * HID + h * 64 + lg * 8;
        const ushort* qpB = Q + (size_t)(b * S_LEN + qrowB) * HID + h * 64 + lg * 8;
        bf16x8 qfA0 = *(const bf16x8*)qpA, qfA1 = *(const bf16x8*)(qpA + 32);
        bf16x8 qfB0 = *(const bf16x8*)qpB, qfB1 = *(const bf16x8*)(qpB + 32);
        ropeq(qfA0, qfA1, qrowA);
        ropeq(qfB0, qfB1, qrowB);
        asm volatile("s_waitcnt vmcnt(0)" ::: "memory");

        f32x4 aoA[4] = {}, aoB[4] = {};
        f32x4 lsumA = {}, lsumB = {};

        auto stage128 = [&](int buf, int tIdx) {
#pragma unroll
            for (int hh = 0; hh < 2; hh++) {
                const int kv0 = tIdx * 128 + hh * 64;
#pragma unroll
                for (int j = 0; j < 2; j++) {
                    gl_lds16(kSrc[j] + (size_t)kv0 * 512, &K_lds[buf][hh][dstU[j]]);
                    gl_lds16(vSrc[j] + kv0, &V_lds[buf][hh][dstU[j]]);
                }
            }
        };

        stage128(0, 0);

        // one subphase: QK + exp + lsum + PV for active subtiles
        auto subphase = [&](const char* Kt, const char* Vl, bool doA, bool mA, bool mB) {
            bf16x8 kf0[4], kf1[4];
#pragma unroll
            for (int kc = 0; kc < 4; kc++) {
                const int kcst = 4096 * (kc >> 1) + 512 * (kc & 1);
                kf0[kc] = *(const bf16x8*)(Kt + kb0 + kcst);
                kf1[kc] = *(const bf16x8*)(Kt + kb1 + kcst);
            }
            f32x4 sB[4], sA[4];
#pragma unroll
            for (int kc = 0; kc < 4; kc++) {
                f32x4 z = {};
                z = __builtin_amdgcn_mfma_f32_16x16x32_bf16(kf0[kc], qfB0, z, 0, 0, 0);
                z = __builtin_amdgcn_mfma_f32_16x16x32_bf16(kf1[kc], qfB1, z, 0, 0, 0);
                sB[kc] = z;
            }
            if (doA) {
#pragma unroll
                for (int kc = 0; kc < 4; kc++) {
                    f32x4 z = {};
                    z = __builtin_amdgcn_mfma_f32_16x16x32_bf16(kf0[kc], qfA0, z, 0, 0, 0);
                    z = __builtin_amdgcn_mfma_f32_16x16x32_bf16(kf1[kc], qfA1, z, 0, 0, 0);
                    sA[kc] = z;
                }
            }
            if (mB) {
#pragma unroll
                for (int kc = 0; kc < 4; kc++)
#pragma unroll
                    for (int r = 0; r < 4; r++) {
                        int kvp = ((kc >> 1) << 5) + (lg << 3) + ((kc & 1) << 2) + r;
                        sB[kc][r] = (kvp <= mloc) ? sB[kc][r] : -INFINITY;
                    }
            }
            if (doA && mA) {
#pragma unroll
                for (int kc = 0; kc < 4; kc++)
#pragma unroll
                    for (int r = 0; r < 4; r++) {
                        int kvp = ((kc >> 1) << 5) + (lg << 3) + ((kc & 1) << 2) + r;
                        sA[kc][r] = (kvp <= mloc) ? sA[kc][r] : -INFINITY;
                    }
            }
            bf16x8 pB0, pB1, pA0, pA1;
#pragma unroll
            for (int r = 0; r < 4; r++) {
                pB0[r]     = (__bf16)ex2(sB[0][r]);
                pB0[4 + r] = (__bf16)ex2(sB[1][r]);
                pB1[r]     = (__bf16)ex2(sB[2][r]);
                pB1[4 + r] = (__bf16)ex2(sB[3][r]);
            }
            if (doA) {
#pragma unroll
                for (int r = 0; r < 4; r++) {
                    pA0[r]     = (__bf16)ex2(sA[0][r]);
                    pA0[4 + r] = (__bf16)ex2(sA[1][r]);
                    pA1[r]     = (__bf16)ex2(sA[2][r]);
                    pA1[4 + r] = (__bf16)ex2(sA[3][r]);
                }
            }
            lsumB = __builtin_amdgcn_mfma_f32_16x16x32_bf16(pB0, onesf, lsumB, 0, 0, 0);
            lsumB = __builtin_amdgcn_mfma_f32_16x16x32_bf16(pB1, onesf, lsumB, 0, 0, 0);
            if (doA) {
                lsumA = __builtin_amdgcn_mfma_f32_16x16x32_bf16(pA0, onesf, lsumA, 0, 0, 0);
                lsumA = __builtin_amdgcn_mfma_f32_16x16x32_bf16(pA1, onesf, lsumA, 0, 0, 0);
            }
#pragma unroll
            for (int dt = 0; dt < 4; dt++) {
                bf16x8 vf0 = *(const bf16x8*)(Vl + vb0 + dt * 2048);
                bf16x8 vf1 = *(const bf16x8*)(Vl + vb1 + dt * 2048);
                aoB[dt] = __builtin_amdgcn_mfma_f32_16x16x32_bf16(pB0, vf0, aoB[dt], 0, 0, 0);
                aoB[dt] = __builtin_amdgcn_mfma_f32_16x16x32_bf16(pB1, vf1, aoB[dt], 0, 0, 0);
                if (doA) {
                    aoA[dt] = __builtin_amdgcn_mfma_f32_16x16x32_bf16(pA0, vf0, aoA[dt], 0, 0, 0);
                    aoA[dt] = __builtin_amdgcn_mfma_f32_16x16x32_bf16(pA1, vf1, aoA[dt], 0, 0, 0);
                }
            }
        };

        for (int t = 0; t < TL; ++t) {
            asm volatile("s_waitcnt vmcnt(0)" ::: "memory");
            __builtin_amdgcn_s_barrier();
            if (t + 1 < TL) stage128((t + 1) & 1, t + 1);

            const bool lastT = (t == TL - 1);
            const char* Kt0 = (const char*)&K_lds[t & 1][0][0];
            const char* Vl0 = (const char*)&V_lds[t & 1][0][0];
            const char* Kt1 = (const char*)&K_lds[t & 1][1][0];
            const char* Vl1 = (const char*)&V_lds[t & 1][1][0];

            // h64 = 0: A masked if last tile; B unmasked
            subphase(Kt0, Vl0, true, lastT, false);
            // h64 = 1: if last tile, A fully masked -> skip; B masked
            if (!lastT) subphase(Kt1, Vl1, true, false, false);
            else        subphase(Kt1, Vl1, false, false, true);
        }

        float invA[4], invB[4];
#pragma unroll
        for (int r = 0; r < 4; r++) { invA[r] = 1.0f / lsumA[r]; invB[r] = 1.0f / lsumB[r]; }
        ushort* obA = O + (size_t)(b * S_LEN + q0A + lg * 4) * HID + h * 64 + l15;
        ushort* obB = O + (size_t)(b * S_LEN + q0B + lg * 4) * HID + h * 64 + l15;
#pragma unroll
        for (int dt = 0; dt < 4; dt++)
#pragma unroll
            for (int r = 0; r < 4; r++) {
                union { __bf16 h; ushort u; } cA{(__bf16)(aoA[dt][r] * invA[r])};
                union { __bf16 h; ushort u; } cB{(__bf16)(aoB[dt][r] * invB[r])};
                obA[(size_t)r * HID + dt * 16] = cA.u;
                obB[(size_t)r * HID + dt * 16] = cB.u;
            }

        // protect LDS buffer reuse across halves
        __builtin_amdgcn_s_barrier();
    }
}

// ---------------- launch ----------------
extern "C" void kernel_launch(void* const* d_in, const int* in_sizes, int n_in,
                              void* d_out, int out_size, void* d_ws, size_t ws_size,
                              hipStream_t stream) {
    const float* hidden = (const float*)d_in[0];
    const float* Wq = (const float*)d_in[1];
    const float* Wk = (const float*)d_in[2];
    const float* Wv = (const float*)d_in[3];
    const float* Wo = (const float*)d_in[4];

    char* ws = (char*)d_ws;
    size_t off = 0;
    auto alloc = [&](size_t bytes) -> void* {
        void* p = ws + off;
        off += (bytes + 255) & ~(size_t)255;
        return p;
    };
    ushort* hb   = (ushort*)alloc((size_t)NTOK * HID * 2);
    ushort* wqkv = (ushort*)alloc((size_t)NQKV * 2048 * 2);
    ushort* wo   = (ushort*)alloc((size_t)2048 * 2048 * 2);
    ushort* Qb   = (ushort*)alloc((size_t)NTOK * 2048 * 2);
    ushort* Kb   = (ushort*)alloc((size_t)NTOK * 512 * 2);
    ushort* Vb   = (ushort*)alloc((size_t)NTOK * 512 * 2);
    ushort* Vtb  = (ushort*)alloc((size_t)NTOK * 512 * 2);
    ushort* AO   = (ushort*)alloc((size_t)NTOK * 2048 * 2);

    cvt_all<<<2304, 256, 0, stream>>>(hidden, Wq, Wk, Wv, Wo, hb, wqkv, wo);

    // QKV: 256x192 tiles -> 16x16 = 256 blocks (1/CU)
    gemmQKV<<<dim3(16, 16), 512, 0, stream>>>(hb, wqkv, Qb, Kb, Vb, NTOK, NQKV, 2048);

    rope_k<<<(NTOK * 32) / 256, 256, 0, stream>>>(Kb);

    transpose_v<<<dim3(S_LEN / 32, 2, BATCH * NKV), 256, 0, stream>>>(Vb, Vtb);

    attn_k<<<dim3(8, BATCH * NH), 256, 0, stream>>>(Qb, Kb, Vtb, AO);

    // O: 128x256 tiles -> 8x32 = 256 blocks (1/CU)
    gemmO<<<dim3(8, 32), 512, 0, stream>>>(AO, wo, (float*)d_out, NTOK, 2048, 2048);
}

// Round 20
// 159.481 us; speedup vs baseline: 1.0099x; 1.0099x over previous
//
#include <hip/hip_runtime.h>

#define S_LEN 2048
#define BATCH 2
#define NH 32
#define NKV 8
#define HD 64
#define HID 2048
#define NTOK (BATCH * S_LEN)   // 4096
#define NQKV 3072              // 2048 Q + 512 K + 512 V
#define SC_Q 0.18033688011112042f   // 0.125 * log2(e)

typedef __attribute__((ext_vector_type(8))) __bf16 bf16x8;
typedef __attribute__((ext_vector_type(4))) float f32x4;
typedef __attribute__((ext_vector_type(4))) float f32x4v;
typedef __attribute__((ext_vector_type(4))) ushort u16x4;

__device__ inline ushort f2b(float f) {
    union { float f; unsigned u; } x{f};
    unsigned r = (x.u + 0x7fff + ((x.u >> 16) & 1)) >> 16;
    return (ushort)r;
}
__device__ inline float b2f(ushort u) {
    union { unsigned u; float f; } x{(unsigned)u << 16};
    return x.f;
}
__device__ inline float ex2(float x) { return __builtin_amdgcn_exp2f(x); }

// ---------------- fused fp32 -> bf16 conversion (grid-stride, nt loads) ----------------
// Order: hidden, Wq, Wk, Wv first (gemmQKV inputs), Wo last.
__global__ __launch_bounds__(256) void cvt_all(const float* __restrict__ hidden,
                                               const float* __restrict__ Wq,
                                               const float* __restrict__ Wk,
                                               const float* __restrict__ Wv,
                                               const float* __restrict__ Wo,
                                               ushort* __restrict__ hb,
                                               ushort* __restrict__ wqkv,
                                               ushort* __restrict__ wo) {
    for (int bid = blockIdx.x; bid < 18432; bid += gridDim.x) {
        const float* src;
        ushort* dst;
        int off;
        if (bid < 8192)        { src = hidden; dst = hb;                              off = bid; }
        else if (bid < 12288)  { src = Wq;     dst = wqkv;                            off = bid - 8192; }
        else if (bid < 13312)  { src = Wk;     dst = wqkv + (size_t)2048 * 2048;      off = bid - 12288; }
        else if (bid < 14336)  { src = Wv;     dst = wqkv + (size_t)2560 * 2048;      off = bid - 13312; }
        else                   { src = Wo;     dst = wo;                              off = bid - 14336; }
        size_t i = (size_t)off * 256 + threadIdx.x;
        f32x4v v = __builtin_nontemporal_load((const f32x4v*)src + i);
        u16x4 o = {f2b(v[0]), f2b(v[1]), f2b(v[2]), f2b(v[3])};
        *((u16x4*)dst + i) = o;
    }
}

// ---------------- global -> LDS async helper ----------------
__device__ inline void gl_lds16(const void* g, void* l) {
    __builtin_amdgcn_global_load_lds((const __attribute__((address_space(1))) void*)g,
                                     (__attribute__((address_space(3))) void*)l, 16, 0, 0);
}

// ---------------- QKV GEMM: 256x192, 8 waves, SINGLE barrier per K-tile ----------------
__global__ __launch_bounds__(512, 2) void gemmQKV(const ushort* __restrict__ A,
                                                  const ushort* __restrict__ B,
                                                  ushort* __restrict__ Qd,
                                                  ushort* __restrict__ Kd,
                                                  ushort* __restrict__ Vd,
                                                  int M, int N, int K) {
    constexpr int CF = 3;
    constexpr int ABYTES = 256 * 64 * 2;   // 32 KB
    constexpr int BBYTES = 192 * 64 * 2;   // 24 KB
    __shared__ __align__(16) char lds[2][ABYTES + BBYTES];   // 112 KB
    const int tid = threadIdx.x, lane = tid & 63, w = tid >> 6;
    const int wm = w >> 2, wn = w & 3, l15 = lane & 15, lg = lane >> 4;

    const int nbx = gridDim.x;
    int lid = blockIdx.y * nbx + blockIdx.x;
    const int cpx = (nbx * gridDim.y) >> 3;
    int swzb = (lid & 7) * cpx + (lid >> 3);
    const int m0 = (swzb / nbx) * 256, n0 = (swzb % nbx) * (CF * 64);

    const int srow = tid >> 3;
    const int scol = ((tid & 7) ^ (srow & 7)) * 8;
    const ushort* Ag = A + (size_t)(m0 + srow) * K + scol;
    const ushort* Bg = B + (size_t)(n0 + srow) * K + scol;

    auto stage = [&](int buf, int k0) {
        char* base = &lds[buf][0];
#pragma unroll
        for (int j = 0; j < CF; j++)
            gl_lds16(Bg + (size_t)(j * 64) * K + k0, base + ABYTES + (j * 64 + w * 8) * 128);
#pragma unroll
        for (int j = 0; j < 4; j++)
            gl_lds16(Ag + (size_t)(j * 64) * K + k0, base + (j * 64 + w * 8) * 128);
    };

    f32x4 acc[8][CF] = {};

    stage(0, 0);

    const int NT = K >> 6;
    const int sw = (l15 & 7) * 16;
    const int po0 = (lg * 16) ^ sw, po1 = (64 + lg * 16) ^ sw;

    for (int t = 0; t < NT; ++t) {
        asm volatile("s_waitcnt vmcnt(0)" ::: "memory");
        __builtin_amdgcn_s_barrier();
        __builtin_amdgcn_sched_barrier(0);
        if (t + 1 < NT) stage((t + 1) & 1, (t + 1) << 6);
        __builtin_amdgcn_sched_barrier(0);

        const char* pa = &lds[t & 1][0] + (wm * 128 + l15) * 128;
        const char* pb = &lds[t & 1][ABYTES] + (wn * CF * 16 + l15) * 128;

        bf16x8 bf_[2][CF];
#pragma unroll
        for (int j = 0; j < CF; j++) {
            bf_[0][j] = *(const bf16x8*)(pb + j * 2048 + po0);
            bf_[1][j] = *(const bf16x8*)(pb + j * 2048 + po1);
        }
        bf16x8 a_[2][8];
#pragma unroll
        for (int i = 0; i < 8; i++) {
            a_[0][i] = *(const bf16x8*)(pa + i * 2048 + po0);
            a_[1][i] = *(const bf16x8*)(pa + i * 2048 + po1);
        }
        __builtin_amdgcn_s_setprio(1);
#pragma unroll
        for (int ks = 0; ks < 2; ks++)
#pragma unroll
            for (int i = 0; i < 8; i++)
#pragma unroll
                for (int j = 0; j < CF; j++)
                    acc[i][j] = __builtin_amdgcn_mfma_f32_16x16x32_bf16(a_[ks][i], bf_[ks][j], acc[i][j], 0, 0, 0);
        __builtin_amdgcn_s_setprio(0);
    }

    const int mr = m0 + wm * 128 + lg * 4;
#pragma unroll
    for (int j = 0; j < CF; j++) {
        int cb = n0 + wn * CF * 16 + j * 16;
        ushort* dst;
        int dstride, colb;
        if (cb < 2048)      { dst = Qd; dstride = 2048; colb = cb + l15; }
        else if (cb < 2560) { dst = Kd; dstride = 512;  colb = cb - 2048 + l15; }
        else                { dst = Vd; dstride = 512;  colb = cb - 2560 + l15; }
#pragma unroll
        for (int i = 0; i < 8; i++)
#pragma unroll
            for (int r = 0; r < 4; r++)
                dst[(size_t)(mr + i * 16 + r) * dstride + colb] = f2b(acc[i][j][r]);
    }
}

// ---------------- O GEMM: 128x256, 8 waves, 3-buffer 2-deep, SINGLE barrier ----------------
__global__ __launch_bounds__(512, 2) void gemmO(const ushort* __restrict__ A,
                                                const ushort* __restrict__ B,
                                                float* __restrict__ C,
                                                int M, int N, int K) {
    constexpr int ABYTES = 128 * 64 * 2;   // 16 KB
    constexpr int BBYTES = 256 * 64 * 2;   // 32 KB
    __shared__ __align__(16) char lds[3][ABYTES + BBYTES];   // 144 KB
    const int tid = threadIdx.x, lane = tid & 63, w = tid >> 6;
    const int wm = w >> 2, wn = w & 3, l15 = lane & 15, lg = lane >> 4;

    const int nbx = gridDim.x;   // 8
    int lid = blockIdx.y * nbx + blockIdx.x;
    const int cpx = (nbx * gridDim.y) >> 3;   // 32
    int swzb = (lid & 7) * cpx + (lid >> 3);
    const int m0 = (swzb / nbx) * 128, n0 = (swzb % nbx) * 256;

    const int srow = tid >> 3;
    const int scol = ((tid & 7) ^ (srow & 7)) * 8;
    const ushort* Ag = A + (size_t)(m0 + srow) * K + scol;
    const ushort* Bg = B + (size_t)(n0 + srow) * K + scol;

    auto stage = [&](int buf, int k0) {
        char* base = &lds[buf][0];
        gl_lds16(Ag + k0,                   base + (w * 8) * 128);
        gl_lds16(Ag + (size_t)64 * K + k0,  base + (64 + w * 8) * 128);
#pragma unroll
        for (int j = 0; j < 4; j++)
            gl_lds16(Bg + (size_t)(j * 64) * K + k0, base + ABYTES + (j * 64 + w * 8) * 128);
    };

    f32x4 acc[4][4] = {};

    stage(0, 0);
    stage(1, 64);

    const int NT = K >> 6;
    const int sw = (l15 & 7) * 16;
    const int po0 = (lg * 16) ^ sw, po1 = (64 + lg * 16) ^ sw;

    int i0 = 0, i1 = 1, i2 = 2;
    for (int t = 0; t < NT; ++t) {
        if (t < NT - 1) asm volatile("s_waitcnt vmcnt(6)" ::: "memory");
        else            asm volatile("s_waitcnt vmcnt(0)" ::: "memory");
        __builtin_amdgcn_s_barrier();
        __builtin_amdgcn_sched_barrier(0);
        if (t + 2 < NT) stage(i2, (t + 2) << 6);
        __builtin_amdgcn_sched_barrier(0);

        const char* pa = &lds[i0][0] + (wm * 64 + l15) * 128;
        const char* pb = &lds[i0][ABYTES] + (wn * 64 + l15) * 128;

        bf16x8 a_[2][4], b_[2][4];
#pragma unroll
        for (int i = 0; i < 4; i++) {
            a_[0][i] = *(const bf16x8*)(pa + i * 2048 + po0);
            a_[1][i] = *(const bf16x8*)(pa + i * 2048 + po1);
            b_[0][i] = *(const bf16x8*)(pb + i * 2048 + po0);
            b_[1][i] = *(const bf16x8*)(pb + i * 2048 + po1);
        }
        __builtin_amdgcn_s_setprio(1);
#pragma unroll
        for (int ks = 0; ks < 2; ks++)
#pragma unroll
            for (int i = 0; i < 4; i++)
#pragma unroll
                for (int j = 0; j < 4; j++)
                    acc[i][j] = __builtin_amdgcn_mfma_f32_16x16x32_bf16(a_[ks][i], b_[ks][j], acc[i][j], 0, 0, 0);
        __builtin_amdgcn_s_setprio(0);

        int tt = i0; i0 = i1; i1 = i2; i2 = tt;
    }

    const int mr = m0 + wm * 64 + lg * 4, nc = n0 + wn * 64 + l15;
#pragma unroll
    for (int i = 0; i < 4; i++)
#pragma unroll
        for (int j = 0; j < 4; j++)
#pragma unroll
            for (int r = 0; r < 4; r++)
                C[(size_t)(mr + i * 16 + r) * N + nc + j * 16] = acc[i][j][r];
}

// ---------------- fused K-RoPE + V-transpose ----------------
// grid (64, 2, 20): z<16 -> V transpose tiles (b=z>>3, kvh=z&7);
// z>=16 -> K rope blocks (512 total: (z-16)*128 + y*64 + x).
__global__ __launch_bounds__(256) void prep_kv(ushort* __restrict__ Kb,
                                               const ushort* __restrict__ V,
                                               ushort* __restrict__ Vt) {
    int bz = blockIdx.z;
    if (bz < 16) {
        __shared__ ushort tile[32][33];
        int b = bz >> 3, kvh = bz & 7;
        int s0 = blockIdx.x * 32, d0 = blockIdx.y * 32;
        int tx = threadIdx.x & 31, ty = threadIdx.x >> 5;
#pragma unroll
        for (int i = 0; i < 4; i++)
            tile[ty + i * 8][tx] = V[(size_t)(b * S_LEN + s0 + ty + i * 8) * 512 + kvh * 64 + d0 + tx];
        __syncthreads();
#pragma unroll
        for (int i = 0; i < 4; i++)
            Vt[((size_t)((b * 8 + kvh) * 64 + d0 + ty + i * 8)) * S_LEN + s0 + tx] = tile[tx][ty + i * 8];
        return;
    }
    // ---- K rope ----
    int rb = (bz - 16) * 128 + blockIdx.y * 64 + blockIdx.x;   // 0..511
    int idx = rb * 256 + threadIdx.x;                          // NTOK * 8 * 4
    int t = idx >> 5, rem = idx & 31;
    int hh = rem >> 2, q8 = rem & 3;
    float pos = (float)(t & (S_LEN - 1));
    ushort* base = Kb + (size_t)t * 512 + hh * 64 + q8 * 8;
    ushort4 v0 = *(ushort4*)base, v1 = *(ushort4*)(base + 4);
    ushort4 u0 = *(ushort4*)(base + 32), u1 = *(ushort4*)(base + 36);
    ushort lo[8] = {v0.x, v0.y, v0.z, v0.w, v1.x, v1.y, v1.z, v1.w};
    ushort hi[8] = {u0.x, u0.y, u0.z, u0.w, u1.x, u1.y, u1.z, u1.w};
#pragma unroll
    for (int e = 0; e < 8; e++) {
        float f = ex2(-(float)(q8 * 8 + e) * 0.4152410118609203f);
        float sv, cv;
        __sincosf(pos * f, &sv, &cv);
        float x1 = b2f(lo[e]), x2 = b2f(hi[e]);
        lo[e] = f2b(x1 * cv - x2 * sv);
        hi[e] = f2b(x2 * cv + x1 * sv);
    }
    *(ushort4*)base        = make_ushort4(lo[0], lo[1], lo[2], lo[3]);
    *(ushort4*)(base + 4)  = make_ushort4(lo[4], lo[5], lo[6], lo[7]);
    *(ushort4*)(base + 32) = make_ushort4(hi[0], hi[1], hi[2], hi[3]);
    *(ushort4*)(base + 36) = make_ushort4(hi[4], hi[5], hi[6], hi[7]);
}

// ---------------- Flash attention (causal, GQA) ----------------
// KVBLK=128 (two 64-kv sub-buffers), one vmcnt(0)+barrier per 128-tile,
// 2 q-subtiles/wave, no online max, row sums via MFMA-ones, Q roped in-reg.
__global__ __launch_bounds__(256) void attn_k(const ushort* __restrict__ Q,   // stride 2048
                                              const ushort* __restrict__ Kc,  // stride 512 (roped)
                                              const ushort* __restrict__ Vt,
                                              ushort* __restrict__ O) {
    __shared__ __align__(16) ushort K_lds[2][2][4096];   // 32 KB
    __shared__ __align__(16) ushort V_lds[2][2][4096];   // 32 KB
    const int lane = threadIdx.x & 63, w = threadIdx.x >> 6;
    const int l15 = lane & 15, lg = lane >> 4;

    int lid = blockIdx.y * 8 + blockIdx.x;
    int swz = (lid & 7) * 64 + (lid >> 3);
    const int ps = swz & 7;
    const int bh = swz >> 3;
    const int b = bh >> 5, h = bh & 31, kvh = h >> 2;

    const ushort* kSrc[2];
    const ushort* vSrc[2];
    int dstU[2];
#pragma unroll
    for (int j = 0; j < 2; j++) {
        int u = w * 2 + j;
        int row = u * 8 + (lane >> 3);
        int po = (lane & 7) * 16;
        int fr = ((row & 3) | (((row >> 3) & 1) << 2)) << 4;
        int dus = (po ^ fr) >> 1;
        kSrc[j] = Kc + (size_t)(b * S_LEN + row) * 512 + kvh * 64 + dus;
        vSrc[j] = Vt + ((size_t)((b * 8 + kvh) * 64 + row)) * S_LEN + dus;
        dstU[j] = u * 512;
    }

    int fr_k = ((l15 & 3) | (((l15 >> 2) & 1) << 2)) << 4;
    int kbase = 1024 * (l15 >> 2) + 128 * (l15 & 3) + ((lg * 16) ^ (fr_k & 48));
    int k6 = (fr_k >> 6) & 1;
    int kb0 = kbase + 64 * k6, kb1 = kbase + 64 * (1 - k6);
    int fr_v = ((l15 & 3) | (((l15 >> 3) & 1) << 2)) << 4;
    int vbase = 128 * l15 + ((lg * 16) ^ (fr_v & 48));
    int v6 = (fr_v >> 6) & 1;
    int vb0 = vbase + 64 * v6, vb1 = vbase + 64 * (1 - v6);

    bf16x8 onesf;
#pragma unroll
    for (int i = 0; i < 8; i++) onesf[i] = (__bf16)1.0f;

    auto ropeq = [&](bf16x8& q0, bf16x8& q1, int qrow) {
        float pos = (float)qrow;
#pragma unroll
        for (int e = 0; e < 8; e++) {
            float f = ex2(-(float)(lg * 8 + e) * 0.4152410118609203f);
            float sv, cv;
            __sincosf(pos * f, &sv, &cv);
            float x1 = (float)q0[e], x2 = (float)q1[e];
            q0[e] = (__bf16)((x1 * cv - x2 * sv) * SC_Q);
            q1[e] = (__bf16)((x2 * cv + x1 * sv) * SC_Q);
        }
    };

    const int mloc = w * 16 + l15;

    for (int half = 0; half < 2; ++half) {
        const int pp = half ? (15 - ps) : ps;
        const int q0A = pp * 128 + w * 16, q0B = q0A + 64;
        const int qrowA = q0A + l15, qrowB = q0B + l15;
        const int TL = pp + 1;

        const ushort* qpA = Q + (size_t)(b * S_LEN + qrowA) * HID + h * 64 + lg * 8;
        const ushort* qpB = Q + (size_t)(b * S_LEN + qrowB) * HID + h * 64 + lg * 8;
        bf16x8 qfA0 = *(const bf16x8*)qpA, qfA1 = *(const bf16x8*)(qpA + 32);
        bf16x8 qfB0 = *(const bf16x8*)qpB, qfB1 = *(const bf16x8*)(qpB + 32);
        ropeq(qfA0, qfA1, qrowA);
        ropeq(qfB0, qfB1, qrowB);
        asm volatile("s_waitcnt vmcnt(0)" ::: "memory");

        f32x4 aoA[4] = {}, aoB[4] = {};
        f32x4 lsumA = {}, lsumB = {};

        auto stage128 = [&](int buf, int tIdx) {
#pragma unroll
            for (int hh = 0; hh < 2; hh++) {
                const int kv0 = tIdx * 128 + hh * 64;
#pragma unroll
                for (int j = 0; j < 2; j++) {
                    gl_lds16(kSrc[j] + (size_t)kv0 * 512, &K_lds[buf][hh][dstU[j]]);
                    gl_lds16(vSrc[j] + kv0, &V_lds[buf][hh][dstU[j]]);
                }
            }
        };

        stage128(0, 0);

        auto subphase = [&](const char* Kt, const char* Vl, bool doA, bool mA, bool mB) {
            bf16x8 kf0[4], kf1[4];
#pragma unroll
            for (int kc = 0; kc < 4; kc++) {
                const int kcst = 4096 * (kc >> 1) + 512 * (kc & 1);
                kf0[kc] = *(const bf16x8*)(Kt + kb0 + kcst);
                kf1[kc] = *(const bf16x8*)(Kt + kb1 + kcst);
            }
            f32x4 sB[4], sA[4];
#pragma unroll
            for (int kc = 0; kc < 4; kc++) {
                f32x4 z = {};
                z = __builtin_amdgcn_mfma_f32_16x16x32_bf16(kf0[kc], qfB0, z, 0, 0, 0);
                z = __builtin_amdgcn_mfma_f32_16x16x32_bf16(kf1[kc], qfB1, z, 0, 0, 0);
                sB[kc] = z;
            }
            if (doA) {
#pragma unroll
                for (int kc = 0; kc < 4; kc++) {
                    f32x4 z = {};
                    z = __builtin_amdgcn_mfma_f32_16x16x32_bf16(kf0[kc], qfA0, z, 0, 0, 0);
                    z = __builtin_amdgcn_mfma_f32_16x16x32_bf16(kf1[kc], qfA1, z, 0, 0, 0);
                    sA[kc] = z;
                }
            }
            if (mB) {
#pragma unroll
                for (int kc = 0; kc < 4; kc++)
#pragma unroll
                    for (int r = 0; r < 4; r++) {
                        int kvp = ((kc >> 1) << 5) + (lg << 3) + ((kc & 1) << 2) + r;
                        sB[kc][r] = (kvp <= mloc) ? sB[kc][r] : -INFINITY;
                    }
            }
            if (doA && mA) {
#pragma unroll
                for (int kc = 0; kc < 4; kc++)
#pragma unroll
                    for (int r = 0; r < 4; r++) {
                        int kvp = ((kc >> 1) << 5) + (lg << 3) + ((kc & 1) << 2) + r;
                        sA[kc][r] = (kvp <= mloc) ? sA[kc][r] : -INFINITY;
                    }
            }
            bf16x8 pB0, pB1, pA0, pA1;
#pragma unroll
            for (int r = 0; r < 4; r++) {
                pB0[r]     = (__bf16)ex2(sB[0][r]);
                pB0[4 + r] = (__bf16)ex2(sB[1][r]);
                pB1[r]     = (__bf16)ex2(sB[2][r]);
                pB1[4 + r] = (__bf16)ex2(sB[3][r]);
            }
            if (doA) {
#pragma unroll
                for (int r = 0; r < 4; r++) {
                    pA0[r]     = (__bf16)ex2(sA[0][r]);
                    pA0[4 + r] = (__bf16)ex2(sA[1][r]);
                    pA1[r]     = (__bf16)ex2(sA[2][r]);
                    pA1[4 + r] = (__bf16)ex2(sA[3][r]);
                }
            }
            lsumB = __builtin_amdgcn_mfma_f32_16x16x32_bf16(pB0, onesf, lsumB, 0, 0, 0);
            lsumB = __builtin_amdgcn_mfma_f32_16x16x32_bf16(pB1, onesf, lsumB, 0, 0, 0);
            if (doA) {
                lsumA = __builtin_amdgcn_mfma_f32_16x16x32_bf16(pA0, onesf, lsumA, 0, 0, 0);
                lsumA = __builtin_amdgcn_mfma_f32_16x16x32_bf16(pA1, onesf, lsumA, 0, 0, 0);
            }
#pragma unroll
            for (int dt = 0; dt < 4; dt++) {
                bf16x8 vf0 = *(const bf16x8*)(Vl + vb0 + dt * 2048);
                bf16x8 vf1 = *(const bf16x8*)(Vl + vb1 + dt * 2048);
                aoB[dt] = __builtin_amdgcn_mfma_f32_16x16x32_bf16(pB0, vf0, aoB[dt], 0, 0, 0);
                aoB[dt] = __builtin_amdgcn_mfma_f32_16x16x32_bf16(pB1, vf1, aoB[dt], 0, 0, 0);
                if (doA) {
                    aoA[dt] = __builtin_amdgcn_mfma_f32_16x16x32_bf16(pA0, vf0, aoA[dt], 0, 0, 0);
                    aoA[dt] = __builtin_amdgcn_mfma_f32_16x16x32_bf16(pA1, vf1, aoA[dt], 0, 0, 0);
                }
            }
        };

        for (int t = 0; t < TL; ++t) {
            asm volatile("s_waitcnt vmcnt(0)" ::: "memory");
            __builtin_amdgcn_s_barrier();
            if (t + 1 < TL) stage128((t + 1) & 1, t + 1);

            const bool lastT = (t == TL - 1);
            const char* Kt0 = (const char*)&K_lds[t & 1][0][0];
            const char* Vl0 = (const char*)&V_lds[t & 1][0][0];
            const char* Kt1 = (const char*)&K_lds[t & 1][1][0];
            const char* Vl1 = (const char*)&V_lds[t & 1][1][0];

            subphase(Kt0, Vl0, true, lastT, false);
            if (!lastT) subphase(Kt1, Vl1, true, false, false);
            else        subphase(Kt1, Vl1, false, false, true);
        }

        float invA[4], invB[4];
#pragma unroll
        for (int r = 0; r < 4; r++) { invA[r] = 1.0f / lsumA[r]; invB[r] = 1.0f / lsumB[r]; }
        ushort* obA = O + (size_t)(b * S_LEN + q0A + lg * 4) * HID + h * 64 + l15;
        ushort* obB = O + (size_t)(b * S_LEN + q0B + lg * 4) * HID + h * 64 + l15;
#pragma unroll
        for (int dt = 0; dt < 4; dt++)
#pragma unroll
            for (int r = 0; r < 4; r++) {
                union { __bf16 h; ushort u; } cA{(__bf16)(aoA[dt][r] * invA[r])};
                union { __bf16 h; ushort u; } cB{(__bf16)(aoB[dt][r] * invB[r])};
                obA[(size_t)r * HID + dt * 16] = cA.u;
                obB[(size_t)r * HID + dt * 16] = cB.u;
            }

        __builtin_amdgcn_s_barrier();
    }
}

// ---------------- launch ----------------
extern "C" void kernel_launch(void* const* d_in, const int* in_sizes, int n_in,
                              void* d_out, int out_size, void* d_ws, size_t ws_size,
                              hipStream_t stream) {
    const float* hidden = (const float*)d_in[0];
    const float* Wq = (const float*)d_in[1];
    const float* Wk = (const float*)d_in[2];
    const float* Wv = (const float*)d_in[3];
    const float* Wo = (const float*)d_in[4];

    char* ws = (char*)d_ws;
    size_t off = 0;
    auto alloc = [&](size_t bytes) -> void* {
        void* p = ws + off;
        off += (bytes + 255) & ~(size_t)255;
        return p;
    };
    ushort* hb   = (ushort*)alloc((size_t)NTOK * HID * 2);
    ushort* wqkv = (ushort*)alloc((size_t)NQKV * 2048 * 2);
    ushort* wo   = (ushort*)alloc((size_t)2048 * 2048 * 2);
    ushort* Qb   = (ushort*)alloc((size_t)NTOK * 2048 * 2);
    ushort* Kb   = (ushort*)alloc((size_t)NTOK * 512 * 2);
    ushort* Vb   = (ushort*)alloc((size_t)NTOK * 512 * 2);
    ushort* Vtb  = (ushort*)alloc((size_t)NTOK * 512 * 2);
    ushort* AO   = (ushort*)alloc((size_t)NTOK * 2048 * 2);

    cvt_all<<<2304, 256, 0, stream>>>(hidden, Wq, Wk, Wv, Wo, hb, wqkv, wo);

    // QKV: 256x192 tiles -> 16x16 = 256 blocks (1/CU)
    gemmQKV<<<dim3(16, 16), 512, 0, stream>>>(hb, wqkv, Qb, Kb, Vb, NTOK, NQKV, 2048);

    // fused K-RoPE + V-transpose (one launch)
    prep_kv<<<dim3(64, 2, 20), 256, 0, stream>>>(Kb, Vb, Vtb);

    attn_k<<<dim3(8, BATCH * NH), 256, 0, stream>>>(Qb, Kb, Vtb, AO);

    // O: 128x256 tiles -> 8x32 = 256 blocks (1/CU)
    gemmO<<<dim3(8, 32), 512, 0, stream>>>(AO, wo, (float*)d_out, NTOK, 2048, 2048);
}